// Round 1
// baseline (502.178 us; speedup 1.0000x reference)
//
#include <hip/hip_runtime.h>
#include <stdint.h>

#define N 448
#define NN (N*N)          // 200704
#define P 128
#define H 64
#define PN 512            // padded row count for einsum operands
#define CH (PN*N)         // elements per channel matrix = 229376

typedef __attribute__((ext_vector_type(8))) short bf16x8;
typedef __attribute__((ext_vector_type(4))) float f32x4;

__device__ __forceinline__ ushort f2bf(float f) {
    uint u = __builtin_bit_cast(uint, f);
    uint r = u + 0x7FFFu + ((u >> 16) & 1u);
    return (ushort)(r >> 16);
}
__device__ __forceinline__ float bf2f(ushort h) {
    uint u = ((uint)h) << 16;
    return __builtin_bit_cast(float, u);
}
__device__ __forceinline__ float sigmoidf(float x) {
    return 1.0f / (1.0f + __expf(-x));
}

// ---------------- kernel 0: weight prep ----------------
// wfrag layout: [(ct*4+ks)*64 + lane]*8 + b  holds Wcat[k][col], bf16
//   k = ks*32 + 8*(lane>>4) + b ; col = ct*16 + (lane&15)
// Wcat cols: 0-63 g1 | 64-127 l1 | 128-191 g2 | 192-255 l2 | 256-383 eg
__global__ void k_prep(const float* __restrict__ g1w, const float* __restrict__ l1w,
                       const float* __restrict__ g2w, const float* __restrict__ l2w,
                       const float* __restrict__ egw, const float* __restrict__ outw,
                       ushort* __restrict__ wfrag, float* __restrict__ owt) {
    int idx = blockIdx.x*256 + threadIdx.x;
    for (int e = idx; e < 24*4*64*8; e += gridDim.x*256) {
        int b  = e & 7;
        int l  = (e >> 3) & 63;
        int ks = (e >> 9) & 3;
        int ct = e >> 11;
        int k   = ks*32 + 8*(l>>4) + b;
        int col = ct*16 + (l & 15);
        float v;
        if (col < 64)       v = g1w[k*64 + col];
        else if (col < 128) v = l1w[k*64 + col - 64];
        else if (col < 192) v = g2w[k*64 + col - 128];
        else if (col < 256) v = l2w[k*64 + col - 192];
        else                v = egw[k*128 + col - 256];
        wfrag[e] = f2bf(v);
    }
    for (int e = idx; e < 128*64; e += gridDim.x*256) {
        int oc = e >> 6, h = e & 63;
        owt[e] = outw[h*128 + oc];   // owt[oc][h] = out_w[h][oc]
    }
}

// ---------------- kernel 1: LN + projections -> ab1/ab2 (bf16, [c][i][j]) + g_sig ----------------
__global__ __launch_bounds__(256) void k_proj(
    const float* __restrict__ z, const float* __restrict__ mask,
    const float* __restrict__ lnw, const float* __restrict__ lnb,
    const float* __restrict__ g1b, const float* __restrict__ l1b,
    const float* __restrict__ g2b, const float* __restrict__ l2b,
    const float* __restrict__ egb,
    const ushort* __restrict__ wfrag,
    ushort* __restrict__ abt, ushort* __restrict__ gsig)
{
    __shared__ ushort zn[64*128];   // [pos][ch] bf16, XOR-swizzled 16B chunks
    const int t = threadIdx.x;
    const int w = t >> 6, l = t & 63;
    const int i = blockIdx.x / 7, j0 = (blockIdx.x % 7) * 64;

    // --- LN phase: wave w handles local positions w*16..w*16+15 ---
    float lw0 = lnw[2*l], lw1 = lnw[2*l+1];
    float lb0 = lnb[2*l], lb1 = lnb[2*l+1];
    for (int q = 0; q < 16; ++q) {
        int p = w*16 + q;
        const float* zp = z + (size_t)(i*N + j0 + p) * P;
        float2 v = *(const float2*)(zp + 2*l);
        float s = v.x + v.y, sq = v.x*v.x + v.y*v.y;
        #pragma unroll
        for (int d = 1; d < 64; d <<= 1) { s += __shfl_xor(s, d); sq += __shfl_xor(sq, d); }
        float mu   = s * (1.0f/128.0f);
        float var  = sq * (1.0f/128.0f) - mu*mu;
        float rstd = rsqrtf(var + 1e-5f);
        float a0 = (v.x - mu)*rstd*lw0 + lb0;
        float a1 = (v.y - mu)*rstd*lw1 + lb1;
        uint pk = (uint)f2bf(a0) | ((uint)f2bf(a1) << 16);
        uint boff = (uint)p*256u + (((((uint)l>>2) ^ ((uint)p & 7u)) & 15u) << 4) + (((uint)l & 3u) << 2);
        *(uint*)((char*)zn + boff) = pk;
    }
    __syncthreads();

    // --- MFMA phase: wave-specific column tiles ---
    const int half = w & 1, pair = w >> 1;   // pair 0 -> ab1 (g1/l1), 1 -> ab2 (g2/l2)
    int ct[6];
    ct[0] = pair*8 + half*2;  ct[1] = ct[0] + 1;     // gate tiles
    ct[2] = ct[0] + 4;        ct[3] = ct[1] + 4;     // lin tiles
    ct[4] = 16 + w*2;         ct[5] = ct[4] + 1;     // eg tiles

    f32x4 acc[4][6];
    #pragma unroll
    for (int a = 0; a < 4; ++a)
        #pragma unroll
        for (int b = 0; b < 6; ++b) acc[a][b] = (f32x4){0.f,0.f,0.f,0.f};

    const uint lr = l & 15, lk = l >> 4;
    #pragma unroll
    for (int ks = 0; ks < 4; ++ks) {
        bf16x8 af[4];
        #pragma unroll
        for (int mi = 0; mi < 4; ++mi) {
            uint row = mi*16u + lr;
            uint chunk = (uint)(ks*4) + lk;
            af[mi] = *(const bf16x8*)((const char*)zn + row*256u + (((chunk ^ (row & 7u)) & 15u) << 4));
        }
        #pragma unroll
        for (int c = 0; c < 6; ++c) {
            bf16x8 bfr = *(const bf16x8*)(wfrag + ((size_t)(ct[c]*4 + ks)*64 + l)*8);
            #pragma unroll
            for (int mi = 0; mi < 4; ++mi)
                acc[mi][c] = __builtin_amdgcn_mfma_f32_16x16x32_bf16(af[mi], bfr, acc[mi][c], 0,0,0);
        }
    }

    // --- epilogue ---
    float bias[6];
    #pragma unroll
    for (int c = 0; c < 6; ++c) {
        int col = ct[c]*16 + (int)lr;
        float bv;
        if (col < 64)       bv = g1b[col];
        else if (col < 128) bv = l1b[col-64];
        else if (col < 192) bv = g2b[col-128];
        else if (col < 256) bv = l2b[col-192];
        else                bv = egb[col-256];
        bias[c] = bv;
    }
    const float* mrow = mask + (size_t)i*N + j0;
    #pragma unroll
    for (int mi = 0; mi < 4; ++mi) {
        float mv[4];
        #pragma unroll
        for (int r = 0; r < 4; ++r) mv[r] = mrow[mi*16 + (int)lk*4 + r];
        #pragma unroll
        for (int pr = 0; pr < 2; ++pr) {
            int cc = (ct[pr] - pair*8)*16 + (int)lr;    // 0..63 within ab
            ushort4 pk;
            float o0 = sigmoidf(acc[mi][pr][0] + bias[pr]) * (acc[mi][pr+2][0] + bias[pr+2]) * mv[0];
            float o1 = sigmoidf(acc[mi][pr][1] + bias[pr]) * (acc[mi][pr+2][1] + bias[pr+2]) * mv[1];
            float o2 = sigmoidf(acc[mi][pr][2] + bias[pr]) * (acc[mi][pr+2][2] + bias[pr+2]) * mv[2];
            float o3 = sigmoidf(acc[mi][pr][3] + bias[pr]) * (acc[mi][pr+2][3] + bias[pr+2]) * mv[3];
            pk.x = f2bf(o0); pk.y = f2bf(o1); pk.z = f2bf(o2); pk.w = f2bf(o3);
            size_t off = (size_t)(pair*64 + cc)*CH + (size_t)i*N + j0 + mi*16 + (int)lk*4;
            *(ushort4*)(abt + off) = pk;
        }
        #pragma unroll
        for (int e = 0; e < 2; ++e) {
            int cg = w*32 + e*16 + (int)lr;   // 0..127
            #pragma unroll
            for (int r = 0; r < 4; ++r) {
                float sg = sigmoidf(acc[mi][4+e][r] + bias[4+e]);
                int pos = i*N + j0 + mi*16 + (int)lk*4 + r;
                gsig[(size_t)pos*128 + cg] = f2bf(sg);
            }
        }
    }
}

// ---------------- kernel 2: per-channel transpose [c][i][k] -> [c][k][i] ----------------
__global__ __launch_bounds__(256) void k_transpose(const ushort* __restrict__ abt,
                                                   ushort* __restrict__ abtt) {
    int bid = blockIdx.x;
    int tile = bid % 49, a = bid / 49;              // a in 0..127 (both arrays)
    int y0 = (tile / 7) * 64, x0 = (tile % 7) * 64;
    const ushort* src = abt  + (size_t)a*CH;
    ushort*       dst = abtt + (size_t)a*CH;
    __shared__ ushort tl[64][68];
    int t = threadIdx.x;
    #pragma unroll
    for (int q = 0; q < 4; ++q) {
        int f = q*1024 + t*4;
        int r = f >> 6, c4 = f & 63;
        ushort4 v = *(const ushort4*)(src + (size_t)(y0 + r)*N + x0 + c4);
        tl[r][c4] = v.x; tl[r][c4+1] = v.y; tl[r][c4+2] = v.z; tl[r][c4+3] = v.w;
    }
    __syncthreads();
    #pragma unroll
    for (int q = 0; q < 4; ++q) {
        int f = q*1024 + t*4;
        int r = f >> 6, c4 = f & 63;
        ushort4 v;
        v.x = tl[c4][r]; v.y = tl[c4+1][r]; v.z = tl[c4+2][r]; v.w = tl[c4+3][r];
        *(ushort4*)(dst + (size_t)(x0 + r)*N + y0 + c4) = v;
    }
}

// ---------------- kernel 3: triangle einsums (batched NT GEMMs, bf16 MFMA) ----------------
__global__ __launch_bounds__(256) void k_tri(const ushort* __restrict__ abt,
                                             const ushort* __restrict__ abtt,
                                             float* __restrict__ blk) {
    const int bid = blockIdx.x;
    const int c = bid >> 4;
    const int tij = bid & 15;
    const int i0 = (tij >> 2) * 128, j0 = (tij & 3) * 128;
    const int t = threadIdx.x, w = t >> 6, l = t & 63;
    const int wr = w >> 1, wc = w & 1;
    const uint lr = l & 15, lk = l >> 4;

    __shared__ ushort lds[4][128*64];   // tA1, tA2, tT1, tT2 ; rows swizzled in 16B chunks

    // wave w stages tile w
    const ushort* basep = (w >= 2) ? abtt : abt;
    const int chan = (w & 1) ? 64 + c : c;
    const int r0   = (w & 1) ? j0 : i0;
    const ushort* sbase = basep + (size_t)chan*CH + (size_t)r0*N;

    f32x4 acc[4][4];
    #pragma unroll
    for (int a = 0; a < 4; ++a)
        #pragma unroll
        for (int b = 0; b < 4; ++b) acc[a][b] = (f32x4){0.f,0.f,0.f,0.f};

    for (int kk = 0; kk < 7; ++kk) {
        __syncthreads();   // previous compute done before overwrite
        const ushort* sb = sbase + kk*64;
        #pragma unroll
        for (int q = 0; q < 16; ++q) {
            int r  = q*8 + (l >> 3);
            int ch = (l & 7) ^ (r & 7);
            const ushort* g = sb + (size_t)r*N + ch*8;
            __builtin_amdgcn_global_load_lds(
                (const __attribute__((address_space(1))) uint*)g,
                (__attribute__((address_space(3))) uint*)(&lds[w][q*512]),
                16, 0, 0);
        }
        __syncthreads();   // staged (syncthreads drains vmcnt)

        #pragma unroll
        for (int ks = 0; ks < 2; ++ks) {
            const uint chunk = (uint)(ks*4) + lk;
            bf16x8 a1[4], b1[4];
            #pragma unroll
            for (int x = 0; x < 4; ++x) {
                uint rowa = (uint)wr*64u + (uint)x*16u + lr;
                uint rowb = (uint)wc*64u + (uint)x*16u + lr;
                a1[x] = *(const bf16x8*)((const char*)lds[0] + rowa*128u + (((chunk ^ (rowa & 7u)) & 15u) << 4));
                b1[x] = *(const bf16x8*)((const char*)lds[1] + rowb*128u + (((chunk ^ (rowb & 7u)) & 15u) << 4));
            }
            #pragma unroll
            for (int mi = 0; mi < 4; ++mi)
                #pragma unroll
                for (int nj = 0; nj < 4; ++nj)
                    acc[mi][nj] = __builtin_amdgcn_mfma_f32_16x16x32_bf16(a1[mi], b1[nj], acc[mi][nj], 0,0,0);

            bf16x8 a2[4], b2[4];
            #pragma unroll
            for (int x = 0; x < 4; ++x) {
                uint rowa = (uint)wr*64u + (uint)x*16u + lr;
                uint rowb = (uint)wc*64u + (uint)x*16u + lr;
                a2[x] = *(const bf16x8*)((const char*)lds[2] + rowa*128u + (((chunk ^ (rowa & 7u)) & 15u) << 4));
                b2[x] = *(const bf16x8*)((const char*)lds[3] + rowb*128u + (((chunk ^ (rowb & 7u)) & 15u) << 4));
            }
            #pragma unroll
            for (int mi = 0; mi < 4; ++mi)
                #pragma unroll
                for (int nj = 0; nj < 4; ++nj)
                    acc[mi][nj] = __builtin_amdgcn_mfma_f32_16x16x32_bf16(a2[mi], b2[nj], acc[mi][nj], 0,0,0);
        }
    }

    #pragma unroll
    for (int mi = 0; mi < 4; ++mi) {
        int ib = i0 + wr*64 + mi*16 + (int)lk*4;
        #pragma unroll
        for (int nj = 0; nj < 4; ++nj) {
            int jb = j0 + wc*64 + nj*16 + (int)lr;
            if (jb < N) {
                #pragma unroll
                for (int r = 0; r < 4; ++r) {
                    int ii = ib + r;
                    if (ii < N) blk[(size_t)c*NN + (size_t)ii*N + jb] = acc[mi][nj][r];
                }
            }
        }
    }
}

// ---------------- kernel 4: LN(block) @ out_w, gate, mask ----------------
__global__ __launch_bounds__(256) void k_out(const float* __restrict__ blk,
    const ushort* __restrict__ gsig, const float* __restrict__ mask,
    const float* __restrict__ lnhw, const float* __restrict__ lnhb,
    const float* __restrict__ owt, const float* __restrict__ outb,
    float* __restrict__ out)
{
    int pos = blockIdx.x*256 + threadIdx.x;
    float v[64];
    float s = 0.f;
    #pragma unroll
    for (int h = 0; h < 64; ++h) { v[h] = blk[(size_t)h*NN + pos]; s += v[h]; }
    float mu = s * (1.0f/64.0f);
    float var = 0.f;
    #pragma unroll
    for (int h = 0; h < 64; ++h) { float d = v[h]-mu; var += d*d; }
    var *= (1.0f/64.0f);
    float rstd = rsqrtf(var + 1e-5f);
    #pragma unroll
    for (int h = 0; h < 64; ++h) v[h] = (v[h]-mu)*rstd*lnhw[h] + lnhb[h];
    float m = mask[pos];
    const ushort* gp = gsig + (size_t)pos*128;
    for (int oc4 = 0; oc4 < 32; ++oc4) {
        float rr[4];
        #pragma unroll
        for (int s4 = 0; s4 < 4; ++s4) {
            int oc = oc4*4 + s4;
            const float* wrow = owt + oc*64;
            float a = 0.f;
            #pragma unroll
            for (int h = 0; h < 64; ++h) a += v[h]*wrow[h];
            rr[s4] = bf2f(gp[oc]) * (a + outb[oc]) * m;
        }
        float4 res = make_float4(rr[0], rr[1], rr[2], rr[3]);
        *(float4*)(out + (size_t)pos*128 + oc4*4) = res;
    }
}

extern "C" void kernel_launch(void* const* d_in, const int* in_sizes, int n_in,
                              void* d_out, int out_size, void* d_ws, size_t ws_size,
                              hipStream_t stream) {
    const float* z    = (const float*)d_in[0];
    const float* mask = (const float*)d_in[1];
    const float* lnw  = (const float*)d_in[2];
    const float* lnb  = (const float*)d_in[3];
    const float* lnhw = (const float*)d_in[4];
    const float* lnhb = (const float*)d_in[5];
    const float* g1w  = (const float*)d_in[6];
    const float* g1b  = (const float*)d_in[7];
    const float* g2w  = (const float*)d_in[8];
    const float* g2b  = (const float*)d_in[9];
    const float* l1w  = (const float*)d_in[10];
    const float* l1b  = (const float*)d_in[11];
    const float* l2w  = (const float*)d_in[12];
    const float* l2b  = (const float*)d_in[13];
    const float* egw  = (const float*)d_in[14];
    const float* egb  = (const float*)d_in[15];
    const float* outw = (const float*)d_in[16];
    const float* outb = (const float*)d_in[17];

    char* ws = (char*)d_ws;
    const size_t SZ_AB = (size_t)2*64*CH*2;          // 58,720,256 B (ab1+ab2, padded rows)
    const size_t SZ_G  = (size_t)NN*128*2;           // 51,380,224 B
    const size_t SZ_BL = (size_t)64*NN*4;            // 51,380,224 B
    ushort* abt   = (ushort*)ws;
    ushort* abtt  = (ushort*)(ws + SZ_AB);
    ushort* gsig  = (ushort*)(ws + 2*SZ_AB);
    float*  blkb  = (float*) (ws + 2*SZ_AB + SZ_G);
    ushort* wfrag = (ushort*)(ws + 2*SZ_AB + SZ_G + SZ_BL);
    float*  owt   = (float*) (ws + 2*SZ_AB + SZ_G + SZ_BL + (size_t)24*4*64*8*2);

    k_prep<<<32, 256, 0, stream>>>(g1w, l1w, g2w, l2w, egw, outw, wfrag, owt);
    k_proj<<<3136, 256, 0, stream>>>(z, mask, lnw, lnb, g1b, l1b, g2b, l2b, egb, wfrag, abt, gsig);
    k_transpose<<<128*49, 256, 0, stream>>>(abt, abtt);
    k_tri<<<64*16, 256, 0, stream>>>(abt, abtt, blkb);
    k_out<<<NN/256, 256, 0, stream>>>(blkb, gsig, mask, lnhw, lnhb, owt, outb, (float*)d_out);
}

// Round 4
// 358.060 us; speedup vs baseline: 1.4025x; 1.4025x over previous
//
#include <hip/hip_runtime.h>
#include <stdint.h>

#define N 448
#define NN (N*N)          // 200704
#define P 128
#define H 64
#define PN 512            // padded row count for einsum operands
#define CH (PN*N)         // elements per channel matrix = 229376

typedef __attribute__((ext_vector_type(8))) short bf16x8;
typedef __attribute__((ext_vector_type(4))) float f32x4;

__device__ __forceinline__ ushort f2bf(float f) {
    uint u = __builtin_bit_cast(uint, f);
    uint r = u + 0x7FFFu + ((u >> 16) & 1u);
    return (ushort)(r >> 16);
}
__device__ __forceinline__ float bf2f(ushort h) {
    uint u = ((uint)h) << 16;
    return __builtin_bit_cast(float, u);
}
__device__ __forceinline__ float sigmoidf(float x) {
    return 1.0f / (1.0f + __expf(-x));
}

// ---------------- kernel 0: weight prep ----------------
// wfrag layout: [(ct*4+ks)*64 + lane]*8 + b  holds Wcat[k][col], bf16
//   k = ks*32 + 8*(lane>>4) + b ; col = ct*16 + (lane&15)
// Wcat cols: 0-63 g1 | 64-127 l1 | 128-191 g2 | 192-255 l2 | 256-383 eg
__global__ void k_prep(const float* __restrict__ g1w, const float* __restrict__ l1w,
                       const float* __restrict__ g2w, const float* __restrict__ l2w,
                       const float* __restrict__ egw,
                       ushort* __restrict__ wfrag) {
    int idx = blockIdx.x*256 + threadIdx.x;
    for (int e = idx; e < 24*4*64*8; e += gridDim.x*256) {
        int b  = e & 7;
        int l  = (e >> 3) & 63;
        int ks = (e >> 9) & 3;
        int ct = e >> 11;
        int k   = ks*32 + 8*(l>>4) + b;
        int col = ct*16 + (l & 15);
        float v;
        if (col < 64)       v = g1w[k*64 + col];
        else if (col < 128) v = l1w[k*64 + col - 64];
        else if (col < 192) v = g2w[k*64 + col - 128];
        else if (col < 256) v = l2w[k*64 + col - 192];
        else                v = egw[k*128 + col - 256];
        wfrag[e] = f2bf(v);
    }
}

// ---------------- kernel 1: LN + projections -> ab1/ab2 (bf16, [c][i][j]) + g_sig ----------------
__global__ __launch_bounds__(256) void k_proj(
    const float* __restrict__ z, const float* __restrict__ mask,
    const float* __restrict__ lnw, const float* __restrict__ lnb,
    const float* __restrict__ g1b, const float* __restrict__ l1b,
    const float* __restrict__ g2b, const float* __restrict__ l2b,
    const float* __restrict__ egb,
    const ushort* __restrict__ wfrag,
    ushort* __restrict__ abt, ushort* __restrict__ gsig)
{
    __shared__ ushort zn[64*128];   // [pos][ch] bf16, XOR-swizzled 16B chunks
    const int t = threadIdx.x;
    const int w = t >> 6, l = t & 63;
    const int i = blockIdx.x / 7, j0 = (blockIdx.x % 7) * 64;

    // --- LN phase: wave w handles local positions w*16..w*16+15 ---
    float lw0 = lnw[2*l], lw1 = lnw[2*l+1];
    float lb0 = lnb[2*l], lb1 = lnb[2*l+1];
    for (int q = 0; q < 16; ++q) {
        int p = w*16 + q;
        const float* zp = z + (size_t)(i*N + j0 + p) * P;
        float2 v = *(const float2*)(zp + 2*l);
        float s = v.x + v.y, sq = v.x*v.x + v.y*v.y;
        #pragma unroll
        for (int d = 1; d < 64; d <<= 1) { s += __shfl_xor(s, d); sq += __shfl_xor(sq, d); }
        float mu   = s * (1.0f/128.0f);
        float var  = sq * (1.0f/128.0f) - mu*mu;
        float rstd = rsqrtf(var + 1e-5f);
        float a0 = (v.x - mu)*rstd*lw0 + lb0;
        float a1 = (v.y - mu)*rstd*lw1 + lb1;
        uint pk = (uint)f2bf(a0) | ((uint)f2bf(a1) << 16);
        uint boff = (uint)p*256u + (((((uint)l>>2) ^ ((uint)p & 7u)) & 15u) << 4) + (((uint)l & 3u) << 2);
        *(uint*)((char*)zn + boff) = pk;
    }
    __syncthreads();

    // --- MFMA phase: wave-specific column tiles ---
    const int half = w & 1, pair = w >> 1;   // pair 0 -> ab1 (g1/l1), 1 -> ab2 (g2/l2)
    int ct[6];
    ct[0] = pair*8 + half*2;  ct[1] = ct[0] + 1;     // gate tiles
    ct[2] = ct[0] + 4;        ct[3] = ct[1] + 4;     // lin tiles
    ct[4] = 16 + w*2;         ct[5] = ct[4] + 1;     // eg tiles

    f32x4 acc[4][6];
    #pragma unroll
    for (int a = 0; a < 4; ++a)
        #pragma unroll
        for (int b = 0; b < 6; ++b) acc[a][b] = (f32x4){0.f,0.f,0.f,0.f};

    const uint lr = l & 15, lk = l >> 4;
    #pragma unroll
    for (int ks = 0; ks < 4; ++ks) {
        bf16x8 af[4];
        #pragma unroll
        for (int mi = 0; mi < 4; ++mi) {
            uint row = mi*16u + lr;
            uint chunk = (uint)(ks*4) + lk;
            af[mi] = *(const bf16x8*)((const char*)zn + row*256u + (((chunk ^ (row & 7u)) & 15u) << 4));
        }
        #pragma unroll
        for (int c = 0; c < 6; ++c) {
            bf16x8 bfr = *(const bf16x8*)(wfrag + ((size_t)(ct[c]*4 + ks)*64 + l)*8);
            #pragma unroll
            for (int mi = 0; mi < 4; ++mi)
                acc[mi][c] = __builtin_amdgcn_mfma_f32_16x16x32_bf16(af[mi], bfr, acc[mi][c], 0,0,0);
        }
    }

    // --- epilogue ---
    float bias[6];
    #pragma unroll
    for (int c = 0; c < 6; ++c) {
        int col = ct[c]*16 + (int)lr;
        float bv;
        if (col < 64)       bv = g1b[col];
        else if (col < 128) bv = l1b[col-64];
        else if (col < 192) bv = g2b[col-128];
        else if (col < 256) bv = l2b[col-192];
        else                bv = egb[col-256];
        bias[c] = bv;
    }
    const float* mrow = mask + (size_t)i*N + j0;
    #pragma unroll
    for (int mi = 0; mi < 4; ++mi) {
        float mv[4];
        #pragma unroll
        for (int r = 0; r < 4; ++r) mv[r] = mrow[mi*16 + (int)lk*4 + r];
        #pragma unroll
        for (int pr = 0; pr < 2; ++pr) {
            int cc = (ct[pr] - pair*8)*16 + (int)lr;    // 0..63 within ab
            ushort4 pk;
            float o0 = sigmoidf(acc[mi][pr][0] + bias[pr]) * (acc[mi][pr+2][0] + bias[pr+2]) * mv[0];
            float o1 = sigmoidf(acc[mi][pr][1] + bias[pr]) * (acc[mi][pr+2][1] + bias[pr+2]) * mv[1];
            float o2 = sigmoidf(acc[mi][pr][2] + bias[pr]) * (acc[mi][pr+2][2] + bias[pr+2]) * mv[2];
            float o3 = sigmoidf(acc[mi][pr][3] + bias[pr]) * (acc[mi][pr+2][3] + bias[pr+2]) * mv[3];
            pk.x = f2bf(o0); pk.y = f2bf(o1); pk.z = f2bf(o2); pk.w = f2bf(o3);
            size_t off = (size_t)(pair*64 + cc)*CH + (size_t)i*N + j0 + mi*16 + (int)lk*4;
            *(ushort4*)(abt + off) = pk;
        }
        #pragma unroll
        for (int e = 0; e < 2; ++e) {
            int cg = w*32 + e*16 + (int)lr;   // 0..127
            #pragma unroll
            for (int r = 0; r < 4; ++r) {
                float sg = sigmoidf(acc[mi][4+e][r] + bias[4+e]) * mv[r];   // mask folded in
                int pos = i*N + j0 + mi*16 + (int)lk*4 + r;
                gsig[(size_t)pos*128 + cg] = f2bf(sg);
            }
        }
    }
}

// ---------------- kernel 2: per-channel transpose [c][i][k] -> [c][k][i] ----------------
__global__ __launch_bounds__(256) void k_transpose(const ushort* __restrict__ abt,
                                                   ushort* __restrict__ abtt) {
    int bid = blockIdx.x;
    int tile = bid % 49, a = bid / 49;              // a in 0..127 (both arrays)
    int y0 = (tile / 7) * 64, x0 = (tile % 7) * 64;
    const ushort* src = abt  + (size_t)a*CH;
    ushort*       dst = abtt + (size_t)a*CH;
    __shared__ ushort tl[64][68];
    int t = threadIdx.x;
    #pragma unroll
    for (int q = 0; q < 4; ++q) {
        int f = q*1024 + t*4;
        int r = f >> 6, c4 = f & 63;
        ushort4 v = *(const ushort4*)(src + (size_t)(y0 + r)*N + x0 + c4);
        tl[r][c4] = v.x; tl[r][c4+1] = v.y; tl[r][c4+2] = v.z; tl[r][c4+3] = v.w;
    }
    __syncthreads();
    #pragma unroll
    for (int q = 0; q < 4; ++q) {
        int f = q*1024 + t*4;
        int r = f >> 6, c4 = f & 63;
        ushort4 v;
        v.x = tl[c4][r]; v.y = tl[c4+1][r]; v.z = tl[c4+2][r]; v.w = tl[c4+3][r];
        *(ushort4*)(dst + (size_t)(x0 + r)*N + y0 + c4) = v;
    }
}

// ---------------- kernel 3: triangle einsums (batched NT GEMMs, bf16 MFMA) ----------------
__global__ __launch_bounds__(256) void k_tri(const ushort* __restrict__ abt,
                                             const ushort* __restrict__ abtt,
                                             float* __restrict__ blk) {
    const int bid = blockIdx.x;
    const int c = bid >> 4;
    const int tij = bid & 15;
    const int i0 = (tij >> 2) * 128, j0 = (tij & 3) * 128;
    const int t = threadIdx.x, w = t >> 6, l = t & 63;
    const int wr = w >> 1, wc = w & 1;
    const uint lr = l & 15, lk = l >> 4;

    __shared__ ushort lds[4][128*64];   // tA1, tA2, tT1, tT2 ; rows swizzled in 16B chunks

    // wave w stages tile w
    const ushort* basep = (w >= 2) ? abtt : abt;
    const int chan = (w & 1) ? 64 + c : c;
    const int r0   = (w & 1) ? j0 : i0;
    const ushort* sbase = basep + (size_t)chan*CH + (size_t)r0*N;

    f32x4 acc[4][4];
    #pragma unroll
    for (int a = 0; a < 4; ++a)
        #pragma unroll
        for (int b = 0; b < 4; ++b) acc[a][b] = (f32x4){0.f,0.f,0.f,0.f};

    for (int kk = 0; kk < 7; ++kk) {
        __syncthreads();   // previous compute done before overwrite
        const ushort* sb = sbase + kk*64;
        #pragma unroll
        for (int q = 0; q < 16; ++q) {
            int r  = q*8 + (l >> 3);
            int ch = (l & 7) ^ (r & 7);
            const ushort* g = sb + (size_t)r*N + ch*8;
            __builtin_amdgcn_global_load_lds(
                (const __attribute__((address_space(1))) uint*)g,
                (__attribute__((address_space(3))) uint*)(&lds[w][q*512]),
                16, 0, 0);
        }
        __syncthreads();   // staged (syncthreads drains vmcnt)

        #pragma unroll
        for (int ks = 0; ks < 2; ++ks) {
            const uint chunk = (uint)(ks*4) + lk;
            bf16x8 a1[4], b1[4];
            #pragma unroll
            for (int x = 0; x < 4; ++x) {
                uint rowa = (uint)wr*64u + (uint)x*16u + lr;
                uint rowb = (uint)wc*64u + (uint)x*16u + lr;
                a1[x] = *(const bf16x8*)((const char*)lds[0] + rowa*128u + (((chunk ^ (rowa & 7u)) & 15u) << 4));
                b1[x] = *(const bf16x8*)((const char*)lds[1] + rowb*128u + (((chunk ^ (rowb & 7u)) & 15u) << 4));
            }
            #pragma unroll
            for (int mi = 0; mi < 4; ++mi)
                #pragma unroll
                for (int nj = 0; nj < 4; ++nj)
                    acc[mi][nj] = __builtin_amdgcn_mfma_f32_16x16x32_bf16(a1[mi], b1[nj], acc[mi][nj], 0,0,0);

            bf16x8 a2[4], b2[4];
            #pragma unroll
            for (int x = 0; x < 4; ++x) {
                uint rowa = (uint)wr*64u + (uint)x*16u + lr;
                uint rowb = (uint)wc*64u + (uint)x*16u + lr;
                a2[x] = *(const bf16x8*)((const char*)lds[2] + rowa*128u + (((chunk ^ (rowa & 7u)) & 15u) << 4));
                b2[x] = *(const bf16x8*)((const char*)lds[3] + rowb*128u + (((chunk ^ (rowb & 7u)) & 15u) << 4));
            }
            #pragma unroll
            for (int mi = 0; mi < 4; ++mi)
                #pragma unroll
                for (int nj = 0; nj < 4; ++nj)
                    acc[mi][nj] = __builtin_amdgcn_mfma_f32_16x16x32_bf16(a2[mi], b2[nj], acc[mi][nj], 0,0,0);
        }
    }

    #pragma unroll
    for (int mi = 0; mi < 4; ++mi) {
        int ib = i0 + wr*64 + mi*16 + (int)lk*4;
        #pragma unroll
        for (int nj = 0; nj < 4; ++nj) {
            int jb = j0 + wc*64 + nj*16 + (int)lr;
            if (jb < N) {
                #pragma unroll
                for (int r = 0; r < 4; ++r) {
                    int ii = ib + r;
                    if (ii < N) blk[(size_t)c*NN + (size_t)ii*N + jb] = acc[mi][nj][r];
                }
            }
        }
    }
}

// ---------------- kernel 4: LN(block) @ out_w in fp32 (VALU), coalesced ----------------
__global__ __launch_bounds__(256) void k_out(const float* __restrict__ blk,
    const ushort* __restrict__ gsig,
    const float* __restrict__ lnhw, const float* __restrict__ lnhb,
    const float* __restrict__ outw, const float* __restrict__ outb,
    float* __restrict__ out)
{
    __shared__ float sblk[64][68];     // [pos][h], 16B-aligned rows
    __shared__ float sW[64*128];       // out_w natural layout [h][col]
    const int t = threadIdx.x;
    const int w = t >> 6, l = t & 63;
    const int pos0 = blockIdx.x * 64;

    // --- stage blk[h][pos0+p] -> sblk[p][h], coalesced float4 reads ---
    #pragma unroll
    for (int q = 0; q < 4; ++q) {
        int flat = q*256 + t;
        int h = flat >> 4, f4 = flat & 15;
        float4 v = *(const float4*)(blk + (size_t)h*NN + pos0 + f4*4);
        sblk[f4*4+0][h] = v.x;
        sblk[f4*4+1][h] = v.y;
        sblk[f4*4+2][h] = v.z;
        sblk[f4*4+3][h] = v.w;
    }
    // --- stage out_w (fp32, no transpose needed) ---
    #pragma unroll
    for (int q = 0; q < 8; ++q) {
        int f = q*1024 + t*4;
        *(float4*)(&sW[f]) = *(const float4*)(outw + f);
    }
    __syncthreads();

    // --- LN over H=64, 4 lanes per position, fp32 in place ---
    {
        int p = w*16 + (l >> 2);
        int sub = l & 3;
        float vv[16];
        float s = 0.f, sq = 0.f;
        #pragma unroll
        for (int j = 0; j < 16; ++j) {
            float x = sblk[p][sub*16 + j];
            vv[j] = x; s += x; sq += x*x;
        }
        s += __shfl_xor(s, 1);  sq += __shfl_xor(sq, 1);
        s += __shfl_xor(s, 2);  sq += __shfl_xor(sq, 2);
        float mu   = s * (1.0f/64.0f);
        float var  = sq * (1.0f/64.0f) - mu*mu;
        float rstd = rsqrtf(var + 1e-5f);
        #pragma unroll
        for (int j = 0; j < 16; ++j) {
            float nv = (vv[j] - mu)*rstd*lnhw[sub*16+j] + lnhb[sub*16+j];
            sblk[p][sub*16 + j] = nv;
        }
    }
    __syncthreads();

    // --- fp32 matvec: thread owns 4 cols (c4..c4+3) x 8 positions ---
    const int c4 = (t & 31) * 4;      // 0..124
    const int prow0 = t >> 5;         // 0..7
    float acc[8][4];
    #pragma unroll
    for (int q = 0; q < 8; ++q)
        #pragma unroll
        for (int j = 0; j < 4; ++j) acc[q][j] = 0.f;

    #pragma unroll
    for (int h4 = 0; h4 < 16; ++h4) {
        float4 wv[4];
        #pragma unroll
        for (int j = 0; j < 4; ++j)
            wv[j] = *(const float4*)(&sW[(h4*4+j)*128 + c4]);
        #pragma unroll
        for (int q = 0; q < 8; ++q) {
            int p = q*8 + prow0;
            float4 av = *(const float4*)(&sblk[p][h4*4]);
            float a0 = av.x, a1 = av.y, a2 = av.z, a3 = av.w;
            acc[q][0] += a0*wv[0].x + a1*wv[1].x + a2*wv[2].x + a3*wv[3].x;
            acc[q][1] += a0*wv[0].y + a1*wv[1].y + a2*wv[2].y + a3*wv[3].y;
            acc[q][2] += a0*wv[0].z + a1*wv[1].z + a2*wv[2].z + a3*wv[3].z;
            acc[q][3] += a0*wv[0].w + a1*wv[1].w + a2*wv[2].w + a3*wv[3].w;
        }
    }

    // --- epilogue: gate (mask pre-folded into gsig) + bias, coalesced float4 stores ---
    float4 ob = *(const float4*)(outb + c4);
    #pragma unroll
    for (int q = 0; q < 8; ++q) {
        size_t pos = (size_t)(pos0 + q*8 + prow0);
        ushort4 gv = *(const ushort4*)(gsig + pos*128 + c4);
        float4 res;
        res.x = bf2f(gv.x) * (acc[q][0] + ob.x);
        res.y = bf2f(gv.y) * (acc[q][1] + ob.y);
        res.z = bf2f(gv.z) * (acc[q][2] + ob.z);
        res.w = bf2f(gv.w) * (acc[q][3] + ob.w);
        *(float4*)(out + pos*128 + c4) = res;
    }
}

extern "C" void kernel_launch(void* const* d_in, const int* in_sizes, int n_in,
                              void* d_out, int out_size, void* d_ws, size_t ws_size,
                              hipStream_t stream) {
    const float* z    = (const float*)d_in[0];
    const float* mask = (const float*)d_in[1];
    const float* lnw  = (const float*)d_in[2];
    const float* lnb  = (const float*)d_in[3];
    const float* lnhw = (const float*)d_in[4];
    const float* lnhb = (const float*)d_in[5];
    const float* g1w  = (const float*)d_in[6];
    const float* g1b  = (const float*)d_in[7];
    const float* g2w  = (const float*)d_in[8];
    const float* g2b  = (const float*)d_in[9];
    const float* l1w  = (const float*)d_in[10];
    const float* l1b  = (const float*)d_in[11];
    const float* l2w  = (const float*)d_in[12];
    const float* l2b  = (const float*)d_in[13];
    const float* egw  = (const float*)d_in[14];
    const float* egb  = (const float*)d_in[15];
    const float* outw = (const float*)d_in[16];
    const float* outb = (const float*)d_in[17];

    char* ws = (char*)d_ws;
    const size_t SZ_AB = (size_t)2*64*CH*2;          // 58,720,256 B (ab1+ab2, padded rows)
    const size_t SZ_G  = (size_t)NN*128*2;           // 51,380,224 B
    const size_t SZ_BL = (size_t)64*NN*4;            // 51,380,224 B
    ushort* abt    = (ushort*)ws;
    ushort* abtt   = (ushort*)(ws + SZ_AB);
    ushort* gsig   = (ushort*)(ws + 2*SZ_AB);
    float*  blkb   = (float*) (ws + 2*SZ_AB + SZ_G);
    ushort* wfrag  = (ushort*)(ws + 2*SZ_AB + SZ_G + SZ_BL);

    k_prep<<<32, 256, 0, stream>>>(g1w, l1w, g2w, l2w, egw, wfrag);
    k_proj<<<3136, 256, 0, stream>>>(z, mask, lnw, lnb, g1b, l1b, g2b, l2b, egb, wfrag, abt, gsig);
    k_transpose<<<128*49, 256, 0, stream>>>(abt, abtt);
    k_tri<<<64*16, 256, 0, stream>>>(abt, abtt, blkb);
    k_out<<<NN/64, 256, 0, stream>>>(blkb, gsig, lnhw, lnhb, outw, outb, (float*)d_out);
}

// Round 5
// 312.192 us; speedup vs baseline: 1.6086x; 1.1469x over previous
//
#include <hip/hip_runtime.h>
#include <stdint.h>

#define N 448
#define NN (N*N)          // 200704
#define P 128
#define H 64
#define PN 512            // padded row count for einsum operands
#define CH (PN*N)         // elements per channel matrix = 229376

typedef __attribute__((ext_vector_type(8))) short bf16x8;
typedef __attribute__((ext_vector_type(4))) float f32x4;

__device__ __forceinline__ ushort f2bf(float f) {
    uint u = __builtin_bit_cast(uint, f);
    uint r = u + 0x7FFFu + ((u >> 16) & 1u);
    return (ushort)(r >> 16);
}
__device__ __forceinline__ float bf2f(ushort h) {
    uint u = ((uint)h) << 16;
    return __builtin_bit_cast(float, u);
}
__device__ __forceinline__ float sigmoidf(float x) {
    return 1.0f / (1.0f + __expf(-x));
}

// ---------------- kernel 0: weight prep ----------------
// wfrag layout: [(ct*4+ks)*64 + lane]*8 + b  holds Wcat[k][col], bf16
//   k = ks*32 + 8*(lane>>4) + b ; col = ct*16 + (lane&15)
// Wcat cols: 0-63 g1 | 64-127 l1 | 128-191 g2 | 192-255 l2 | 256-383 eg
__global__ void k_prep(const float* __restrict__ g1w, const float* __restrict__ l1w,
                       const float* __restrict__ g2w, const float* __restrict__ l2w,
                       const float* __restrict__ egw,
                       ushort* __restrict__ wfrag) {
    int idx = blockIdx.x*256 + threadIdx.x;
    for (int e = idx; e < 24*4*64*8; e += gridDim.x*256) {
        int b  = e & 7;
        int l  = (e >> 3) & 63;
        int ks = (e >> 9) & 3;
        int ct = e >> 11;
        int k   = ks*32 + 8*(l>>4) + b;
        int col = ct*16 + (l & 15);
        float v;
        if (col < 64)       v = g1w[k*64 + col];
        else if (col < 128) v = l1w[k*64 + col - 64];
        else if (col < 192) v = g2w[k*64 + col - 128];
        else if (col < 256) v = l2w[k*64 + col - 192];
        else                v = egw[k*128 + col - 256];
        wfrag[e] = f2bf(v);
    }
}

// ---------------- kernel 1: LN + projections -> ab1/ab2 (bf16, [c][i][j]) + g_sig ----------------
__global__ __launch_bounds__(256) void k_proj(
    const float* __restrict__ z, const float* __restrict__ mask,
    const float* __restrict__ lnw, const float* __restrict__ lnb,
    const float* __restrict__ g1b, const float* __restrict__ l1b,
    const float* __restrict__ g2b, const float* __restrict__ l2b,
    const float* __restrict__ egb,
    const ushort* __restrict__ wfrag,
    ushort* __restrict__ abt, ushort* __restrict__ gsig)
{
    __shared__ ushort zn[64*128];   // [pos][ch] bf16, XOR-swizzled 16B chunks
    __shared__ ushort gs[64][136];  // gsig tile [pos][ch], padded rows (272B, 16B-aligned)
    const int t = threadIdx.x;
    const int w = t >> 6, l = t & 63;
    const int i = blockIdx.x / 7, j0 = (blockIdx.x % 7) * 64;

    // --- LN phase: 4 lanes per position, each owns 32 channels ---
    {
        const int p = t >> 2;          // 0..63 local position
        const int q = t & 3;           // channel quarter
        const float* zp = z + (size_t)(i*N + j0 + p)*P + q*32;
        float4 v[8];
        #pragma unroll
        for (int x = 0; x < 8; ++x) v[x] = *(const float4*)(zp + x*4);
        float s = 0.f, sq = 0.f;
        #pragma unroll
        for (int x = 0; x < 8; ++x) {
            s  += v[x].x + v[x].y + v[x].z + v[x].w;
            sq += v[x].x*v[x].x + v[x].y*v[x].y + v[x].z*v[x].z + v[x].w*v[x].w;
        }
        s += __shfl_xor(s, 1);  sq += __shfl_xor(sq, 1);
        s += __shfl_xor(s, 2);  sq += __shfl_xor(sq, 2);
        float mu   = s * (1.0f/128.0f);
        float var  = sq * (1.0f/128.0f) - mu*mu;
        float rstd = rsqrtf(var + 1e-5f);
        #pragma unroll
        for (int cc = 0; cc < 4; ++cc) {
            int chunk = q*4 + cc;              // 16B chunk index, channels chunk*8..+7
            const float* lwp = lnw + chunk*8;
            const float* lbp = lnb + chunk*8;
            float4 lwa = *(const float4*)(lwp), lwb = *(const float4*)(lwp+4);
            float4 lba = *(const float4*)(lbp), lbb = *(const float4*)(lbp+4);
            float4 va = v[cc*2], vb = v[cc*2+1];
            float n0 = (va.x - mu)*rstd*lwa.x + lba.x;
            float n1 = (va.y - mu)*rstd*lwa.y + lba.y;
            float n2 = (va.z - mu)*rstd*lwa.z + lba.z;
            float n3 = (va.w - mu)*rstd*lwa.w + lba.w;
            float n4 = (vb.x - mu)*rstd*lwb.x + lbb.x;
            float n5 = (vb.y - mu)*rstd*lwb.y + lbb.y;
            float n6 = (vb.z - mu)*rstd*lwb.z + lbb.z;
            float n7 = (vb.w - mu)*rstd*lwb.w + lbb.w;
            uint4 pk;
            pk.x = (uint)f2bf(n0) | ((uint)f2bf(n1) << 16);
            pk.y = (uint)f2bf(n2) | ((uint)f2bf(n3) << 16);
            pk.z = (uint)f2bf(n4) | ((uint)f2bf(n5) << 16);
            pk.w = (uint)f2bf(n6) | ((uint)f2bf(n7) << 16);
            uint boff = (uint)p*256u + (((uint)(chunk ^ (p & 7)) & 15u) << 4);
            *(uint4*)((char*)zn + boff) = pk;
        }
    }
    __syncthreads();

    // --- MFMA phase, group A: gate (2 tiles) + lin (2 tiles) ---
    const int half = w & 1, pair = w >> 1;   // pair 0 -> ab1 (g1/l1), 1 -> ab2 (g2/l2)
    const uint lr = l & 15, lk = l >> 4;
    const int ct0 = pair*8 + half*2;
    int ctA[4] = { ct0, ct0 + 1, ct0 + 4, ct0 + 5 };

    const float* mrow = mask + (size_t)i*N + j0;

    f32x4 accA[4][4];
    #pragma unroll
    for (int a = 0; a < 4; ++a)
        #pragma unroll
        for (int b = 0; b < 4; ++b) accA[a][b] = (f32x4){0.f,0.f,0.f,0.f};

    #pragma unroll
    for (int ks = 0; ks < 4; ++ks) {
        bf16x8 af[4];
        #pragma unroll
        for (int mi = 0; mi < 4; ++mi) {
            uint row = mi*16u + lr;
            uint chunk = (uint)(ks*4) + lk;
            af[mi] = *(const bf16x8*)((const char*)zn + row*256u + (((chunk ^ (row & 7u)) & 15u) << 4));
        }
        #pragma unroll
        for (int c = 0; c < 4; ++c) {
            bf16x8 bfr = *(const bf16x8*)(wfrag + ((size_t)(ctA[c]*4 + ks)*64 + l)*8);
            #pragma unroll
            for (int mi = 0; mi < 4; ++mi)
                accA[mi][c] = __builtin_amdgcn_mfma_f32_16x16x32_bf16(af[mi], bfr, accA[mi][c], 0,0,0);
        }
    }

    // epilogue A: ab1/ab2 stores
    {
        float biasA[4];
        #pragma unroll
        for (int c = 0; c < 4; ++c) {
            int col = ctA[c]*16 + (int)lr;
            float bv;
            if (col < 64)       bv = g1b[col];
            else if (col < 128) bv = l1b[col-64];
            else if (col < 192) bv = g2b[col-128];
            else                bv = l2b[col-192];
            biasA[c] = bv;
        }
        #pragma unroll
        for (int mi = 0; mi < 4; ++mi) {
            float mv[4];
            #pragma unroll
            for (int r = 0; r < 4; ++r) mv[r] = mrow[mi*16 + (int)lk*4 + r];
            #pragma unroll
            for (int pr = 0; pr < 2; ++pr) {
                int cc = (ctA[pr] - pair*8)*16 + (int)lr;    // 0..63 within ab
                ushort4 pk;
                float o0 = sigmoidf(accA[mi][pr][0] + biasA[pr]) * (accA[mi][pr+2][0] + biasA[pr+2]) * mv[0];
                float o1 = sigmoidf(accA[mi][pr][1] + biasA[pr]) * (accA[mi][pr+2][1] + biasA[pr+2]) * mv[1];
                float o2 = sigmoidf(accA[mi][pr][2] + biasA[pr]) * (accA[mi][pr+2][2] + biasA[pr+2]) * mv[2];
                float o3 = sigmoidf(accA[mi][pr][3] + biasA[pr]) * (accA[mi][pr+2][3] + biasA[pr+2]) * mv[3];
                pk.x = f2bf(o0); pk.y = f2bf(o1); pk.z = f2bf(o2); pk.w = f2bf(o3);
                size_t off = (size_t)(pair*64 + cc)*CH + (size_t)i*N + j0 + mi*16 + (int)lk*4;
                *(ushort4*)(abt + off) = pk;
            }
        }
    }

    // --- MFMA phase, group B: eg (2 tiles) ---
    f32x4 accB[4][2];
    #pragma unroll
    for (int a = 0; a < 4; ++a) { accB[a][0] = (f32x4){0,0,0,0}; accB[a][1] = (f32x4){0,0,0,0}; }

    #pragma unroll
    for (int ks = 0; ks < 4; ++ks) {
        bf16x8 af[4];
        #pragma unroll
        for (int mi = 0; mi < 4; ++mi) {
            uint row = mi*16u + lr;
            uint chunk = (uint)(ks*4) + lk;
            af[mi] = *(const bf16x8*)((const char*)zn + row*256u + (((chunk ^ (row & 7u)) & 15u) << 4));
        }
        #pragma unroll
        for (int e = 0; e < 2; ++e) {
            int ct = 16 + w*2 + e;
            bf16x8 bfr = *(const bf16x8*)(wfrag + ((size_t)(ct*4 + ks)*64 + l)*8);
            #pragma unroll
            for (int mi = 0; mi < 4; ++mi)
                accB[mi][e] = __builtin_amdgcn_mfma_f32_16x16x32_bf16(af[mi], bfr, accB[mi][e], 0,0,0);
        }
    }

    // epilogue B: gate sigmoid (mask folded) -> LDS tile
    {
        float biasB[2];
        biasB[0] = egb[(16 + w*2)*16 + (int)lr - 256];
        biasB[1] = egb[(16 + w*2 + 1)*16 + (int)lr - 256];
        #pragma unroll
        for (int mi = 0; mi < 4; ++mi) {
            float mv[4];
            #pragma unroll
            for (int r = 0; r < 4; ++r) mv[r] = mrow[mi*16 + (int)lk*4 + r];
            #pragma unroll
            for (int e = 0; e < 2; ++e) {
                int cg = w*32 + e*16 + (int)lr;   // 0..127
                #pragma unroll
                for (int r = 0; r < 4; ++r) {
                    float sg = sigmoidf(accB[mi][e][r] + biasB[e]) * mv[r];
                    gs[mi*16 + (int)lk*4 + r][cg] = f2bf(sg);
                }
            }
        }
    }
    __syncthreads();

    // coalesced gsig store: thread covers 32 channels of one position
    {
        int p2 = t >> 2, q2 = t & 3;
        size_t pos = (size_t)(i*N + j0 + p2);
        #pragma unroll
        for (int s2 = 0; s2 < 4; ++s2) {
            uint4 vv = *(const uint4*)((const char*)&gs[p2][0] + q2*64 + s2*16);
            *(uint4*)(gsig + pos*128 + q2*32 + s2*8) = vv;
        }
    }
}

// ---------------- kernel 2: per-channel transpose [c][i][k] -> [c][k][i] ----------------
__global__ __launch_bounds__(256) void k_transpose(const ushort* __restrict__ abt,
                                                   ushort* __restrict__ abtt) {
    int bid = blockIdx.x;
    int tile = bid % 49, a = bid / 49;              // a in 0..127 (both arrays)
    int y0 = (tile / 7) * 64, x0 = (tile % 7) * 64;
    const ushort* src = abt  + (size_t)a*CH;
    ushort*       dst = abtt + (size_t)a*CH;
    __shared__ ushort tl[64][68];
    int t = threadIdx.x;
    #pragma unroll
    for (int q = 0; q < 4; ++q) {
        int f = q*1024 + t*4;
        int r = f >> 6, c4 = f & 63;
        ushort4 v = *(const ushort4*)(src + (size_t)(y0 + r)*N + x0 + c4);
        tl[r][c4] = v.x; tl[r][c4+1] = v.y; tl[r][c4+2] = v.z; tl[r][c4+3] = v.w;
    }
    __syncthreads();
    #pragma unroll
    for (int q = 0; q < 4; ++q) {
        int f = q*1024 + t*4;
        int r = f >> 6, c4 = f & 63;
        ushort4 v;
        v.x = tl[c4][r]; v.y = tl[c4+1][r]; v.z = tl[c4+2][r]; v.w = tl[c4+3][r];
        *(ushort4*)(dst + (size_t)(x0 + r)*N + y0 + c4) = v;
    }
}

// ---------------- kernel 3: triangle einsums (batched NT GEMMs, bf16 MFMA) ----------------
__global__ __launch_bounds__(256) void k_tri(const ushort* __restrict__ abt,
                                             const ushort* __restrict__ abtt,
                                             float* __restrict__ blk) {
    // bijective XCD swizzle: 1024 blocks = 8 XCDs x 128; keep one channel's
    // 16 tiles (working set 1.6 MB) resident in one XCD's L2
    int bid = (blockIdx.x & 7)*128 + (blockIdx.x >> 3);
    const int c = bid >> 4;
    const int tij = bid & 15;
    const int i0 = (tij >> 2) * 128, j0 = (tij & 3) * 128;
    const int t = threadIdx.x, w = t >> 6, l = t & 63;
    const int wr = w >> 1, wc = w & 1;
    const uint lr = l & 15, lk = l >> 4;

    __shared__ ushort lds[4][128*64];   // tA1, tA2, tT1, tT2 ; rows swizzled in 16B chunks

    // wave w stages tile w
    const ushort* basep = (w >= 2) ? abtt : abt;
    const int chan = (w & 1) ? 64 + c : c;
    const int r0   = (w & 1) ? j0 : i0;
    const ushort* sbase = basep + (size_t)chan*CH + (size_t)r0*N;

    f32x4 acc[4][4];
    #pragma unroll
    for (int a = 0; a < 4; ++a)
        #pragma unroll
        for (int b = 0; b < 4; ++b) acc[a][b] = (f32x4){0.f,0.f,0.f,0.f};

    for (int kk = 0; kk < 7; ++kk) {
        __syncthreads();   // previous compute done before overwrite
        const ushort* sb = sbase + kk*64;
        #pragma unroll
        for (int q = 0; q < 16; ++q) {
            int r  = q*8 + (l >> 3);
            int ch = (l & 7) ^ (r & 7);
            const ushort* g = sb + (size_t)r*N + ch*8;
            __builtin_amdgcn_global_load_lds(
                (const __attribute__((address_space(1))) uint*)g,
                (__attribute__((address_space(3))) uint*)(&lds[w][q*512]),
                16, 0, 0);
        }
        __syncthreads();   // staged (syncthreads drains vmcnt)

        #pragma unroll
        for (int ks = 0; ks < 2; ++ks) {
            const uint chunk = (uint)(ks*4) + lk;
            bf16x8 a1[4], b1[4];
            #pragma unroll
            for (int x = 0; x < 4; ++x) {
                uint rowa = (uint)wr*64u + (uint)x*16u + lr;
                uint rowb = (uint)wc*64u + (uint)x*16u + lr;
                a1[x] = *(const bf16x8*)((const char*)lds[0] + rowa*128u + (((chunk ^ (rowa & 7u)) & 15u) << 4));
                b1[x] = *(const bf16x8*)((const char*)lds[1] + rowb*128u + (((chunk ^ (rowb & 7u)) & 15u) << 4));
            }
            #pragma unroll
            for (int mi = 0; mi < 4; ++mi)
                #pragma unroll
                for (int nj = 0; nj < 4; ++nj)
                    acc[mi][nj] = __builtin_amdgcn_mfma_f32_16x16x32_bf16(a1[mi], b1[nj], acc[mi][nj], 0,0,0);

            bf16x8 a2[4], b2[4];
            #pragma unroll
            for (int x = 0; x < 4; ++x) {
                uint rowa = (uint)wr*64u + (uint)x*16u + lr;
                uint rowb = (uint)wc*64u + (uint)x*16u + lr;
                a2[x] = *(const bf16x8*)((const char*)lds[2] + rowa*128u + (((chunk ^ (rowa & 7u)) & 15u) << 4));
                b2[x] = *(const bf16x8*)((const char*)lds[3] + rowb*128u + (((chunk ^ (rowb & 7u)) & 15u) << 4));
            }
            #pragma unroll
            for (int mi = 0; mi < 4; ++mi)
                #pragma unroll
                for (int nj = 0; nj < 4; ++nj)
                    acc[mi][nj] = __builtin_amdgcn_mfma_f32_16x16x32_bf16(a2[mi], b2[nj], acc[mi][nj], 0,0,0);
        }
    }

    #pragma unroll
    for (int mi = 0; mi < 4; ++mi) {
        int ib = i0 + wr*64 + mi*16 + (int)lk*4;
        #pragma unroll
        for (int nj = 0; nj < 4; ++nj) {
            int jb = j0 + wc*64 + nj*16 + (int)lr;
            if (jb < N) {
                #pragma unroll
                for (int r = 0; r < 4; ++r) {
                    int ii = ib + r;
                    if (ii < N) blk[(size_t)c*NN + (size_t)ii*N + jb] = acc[mi][nj][r];
                }
            }
        }
    }
}

// ---------------- kernel 4: LN(block) @ out_w in fp32 (VALU), coalesced ----------------
__global__ __launch_bounds__(256) void k_out(const float* __restrict__ blk,
    const ushort* __restrict__ gsig,
    const float* __restrict__ lnhw, const float* __restrict__ lnhb,
    const float* __restrict__ outw, const float* __restrict__ outb,
    float* __restrict__ out)
{
    __shared__ float sblk[64][68];     // [pos][h], 16B-aligned rows
    __shared__ float sW[64*128];       // out_w natural layout [h][col]
    const int t = threadIdx.x;
    const int w = t >> 6, l = t & 63;
    const int pos0 = blockIdx.x * 64;

    // --- stage blk[h][pos0+p] -> sblk[p][h], coalesced float4 reads ---
    #pragma unroll
    for (int q = 0; q < 4; ++q) {
        int flat = q*256 + t;
        int h = flat >> 4, f4 = flat & 15;
        float4 v = *(const float4*)(blk + (size_t)h*NN + pos0 + f4*4);
        sblk[f4*4+0][h] = v.x;
        sblk[f4*4+1][h] = v.y;
        sblk[f4*4+2][h] = v.z;
        sblk[f4*4+3][h] = v.w;
    }
    // --- stage out_w (fp32, no transpose needed) ---
    #pragma unroll
    for (int q = 0; q < 8; ++q) {
        int f = q*1024 + t*4;
        *(float4*)(&sW[f]) = *(const float4*)(outw + f);
    }
    __syncthreads();

    // --- LN over H=64, 4 lanes per position, fp32 in place ---
    {
        int p = w*16 + (l >> 2);
        int sub = l & 3;
        float vv[16];
        float s = 0.f, sq = 0.f;
        #pragma unroll
        for (int j = 0; j < 16; ++j) {
            float x = sblk[p][sub*16 + j];
            vv[j] = x; s += x; sq += x*x;
        }
        s += __shfl_xor(s, 1);  sq += __shfl_xor(sq, 1);
        s += __shfl_xor(s, 2);  sq += __shfl_xor(sq, 2);
        float mu   = s * (1.0f/64.0f);
        float var  = sq * (1.0f/64.0f) - mu*mu;
        float rstd = rsqrtf(var + 1e-5f);
        #pragma unroll
        for (int j = 0; j < 16; ++j) {
            float nv = (vv[j] - mu)*rstd*lnhw[sub*16+j] + lnhb[sub*16+j];
            sblk[p][sub*16 + j] = nv;
        }
    }
    __syncthreads();

    // --- fp32 matvec: thread owns 4 cols (c4..c4+3) x 8 positions ---
    const int c4 = (t & 31) * 4;      // 0..124
    const int prow0 = t >> 5;         // 0..7
    float acc[8][4];
    #pragma unroll
    for (int q = 0; q < 8; ++q)
        #pragma unroll
        for (int j = 0; j < 4; ++j) acc[q][j] = 0.f;

    #pragma unroll
    for (int h4 = 0; h4 < 16; ++h4) {
        float4 wv[4];
        #pragma unroll
        for (int j = 0; j < 4; ++j)
            wv[j] = *(const float4*)(&sW[(h4*4+j)*128 + c4]);
        #pragma unroll
        for (int q = 0; q < 8; ++q) {
            int p = q*8 + prow0;
            float4 av = *(const float4*)(&sblk[p][h4*4]);
            float a0 = av.x, a1 = av.y, a2 = av.z, a3 = av.w;
            acc[q][0] += a0*wv[0].x + a1*wv[1].x + a2*wv[2].x + a3*wv[3].x;
            acc[q][1] += a0*wv[0].y + a1*wv[1].y + a2*wv[2].y + a3*wv[3].y;
            acc[q][2] += a0*wv[0].z + a1*wv[1].z + a2*wv[2].z + a3*wv[3].z;
            acc[q][3] += a0*wv[0].w + a1*wv[1].w + a2*wv[2].w + a3*wv[3].w;
        }
    }

    // --- epilogue: gate (mask pre-folded into gsig) + bias, coalesced float4 stores ---
    float4 ob = *(const float4*)(outb + c4);
    #pragma unroll
    for (int q = 0; q < 8; ++q) {
        size_t pos = (size_t)(pos0 + q*8 + prow0);
        ushort4 gv = *(const ushort4*)(gsig + pos*128 + c4);
        float4 res;
        res.x = bf2f(gv.x) * (acc[q][0] + ob.x);
        res.y = bf2f(gv.y) * (acc[q][1] + ob.y);
        res.z = bf2f(gv.z) * (acc[q][2] + ob.z);
        res.w = bf2f(gv.w) * (acc[q][3] + ob.w);
        *(float4*)(out + pos*128 + c4) = res;
    }
}

extern "C" void kernel_launch(void* const* d_in, const int* in_sizes, int n_in,
                              void* d_out, int out_size, void* d_ws, size_t ws_size,
                              hipStream_t stream) {
    const float* z    = (const float*)d_in[0];
    const float* mask = (const float*)d_in[1];
    const float* lnw  = (const float*)d_in[2];
    const float* lnb  = (const float*)d_in[3];
    const float* lnhw = (const float*)d_in[4];
    const float* lnhb = (const float*)d_in[5];
    const float* g1w  = (const float*)d_in[6];
    const float* g1b  = (const float*)d_in[7];
    const float* g2w  = (const float*)d_in[8];
    const float* g2b  = (const float*)d_in[9];
    const float* l1w  = (const float*)d_in[10];
    const float* l1b  = (const float*)d_in[11];
    const float* l2w  = (const float*)d_in[12];
    const float* l2b  = (const float*)d_in[13];
    const float* egw  = (const float*)d_in[14];
    const float* egb  = (const float*)d_in[15];
    const float* outw = (const float*)d_in[16];
    const float* outb = (const float*)d_in[17];

    char* ws = (char*)d_ws;
    const size_t SZ_AB = (size_t)2*64*CH*2;          // 58,720,256 B (ab1+ab2, padded rows)
    const size_t SZ_G  = (size_t)NN*128*2;           // 51,380,224 B
    const size_t SZ_BL = (size_t)64*NN*4;            // 51,380,224 B
    ushort* abt    = (ushort*)ws;
    ushort* abtt   = (ushort*)(ws + SZ_AB);
    ushort* gsig   = (ushort*)(ws + 2*SZ_AB);
    float*  blkb   = (float*) (ws + 2*SZ_AB + SZ_G);
    ushort* wfrag  = (ushort*)(ws + 2*SZ_AB + SZ_G + SZ_BL);

    k_prep<<<32, 256, 0, stream>>>(g1w, l1w, g2w, l2w, egw, wfrag);
    k_proj<<<3136, 256, 0, stream>>>(z, mask, lnw, lnb, g1b, l1b, g2b, l2b, egb, wfrag, abt, gsig);
    k_transpose<<<128*49, 256, 0, stream>>>(abt, abtt);
    k_tri<<<64*16, 256, 0, stream>>>(abt, abtt, blkb);
    k_out<<<NN/64, 256, 0, stream>>>(blkb, gsig, lnhw, lnhb, outw, outb, (float*)d_out);
}